// Round 12
// baseline (340.415 us; speedup 1.0000x reference)
//
#include <hip/hip_runtime.h>

// ---- fused front-end v5: pw-output split across 2 blocks -> 2048 blocks (8/CU) ----
// blockIdx.x = tile(256)+b*256; blockIdx.y = half. 8x8 px tile, wave = tile.
// half 0: pw outputs 0..31 (wave w: 8 outputs 8w..); half 1: pw 32..63 + red + stats.
__launch_bounds__(256, 4)
__global__ void k_front(const float* __restrict__ in, const float* __restrict__ wdw,
                        const float* __restrict__ wpw, const float* __restrict__ wred,
                        float* __restrict__ h, float* __restrict__ r,
                        float* __restrict__ stats){
  __shared__ float4 s_in4[4][10][12];                // [c4][ry][rx] 4ch contiguous
  __shared__ float4 s_dw4[4][64];                    // [c4][px]
  __shared__ float  s_red[4][8];
  int t = threadIdx.x;
  int w = t >> 6, lane = t & 63;
  int lx = lane & 7, ly = lane >> 3;
  int tile = blockIdx.x & 255, b = blockIdx.x >> 8;
  int half = blockIdx.y;
  int x0 = (tile & 15) << 3, y0 = (tile >> 4) << 3;
  const float* inb = in + ((long)b << 20);

  float pacc[8], racc[4];
  #pragma unroll
  for (int j = 0; j < 8; j++) pacc[j] = 0.f;
  #pragma unroll
  for (int j = 0; j < 4; j++) racc[j] = 0.f;

  for (int q = 0; q < 4; q++){
    int c0 = q << 4;
    __syncthreads();                                 // s_in4 free (prev chunk done)
    for (int i = t; i < 400; i += 256){              // 4 c4-groups x 10x10 halo
      int c4 = i / 100, pos = i - c4 * 100;
      int ry = pos / 10, rx = pos - ry * 10;
      int yy = y0 + ry - 1, xx = x0 + rx - 1;
      float4 v = make_float4(0.f, 0.f, 0.f, 0.f);
      if ((unsigned)yy < 128u && (unsigned)xx < 128u){
        long base = ((long)(c0 + (c4 << 2)) << 14) + (yy << 7) + xx;
        v.x = inb[base];
        v.y = inb[base + 16384];
        v.z = inb[base + 32768];
        v.w = inb[base + 49152];
      }
      s_in4[c4][ry][rx] = v;
    }
    __syncthreads();

    // dw: wave w convolves its 4 channels (c0+4w..+3), once per px
    {
      const float* wd = wdw + (c0 + (w << 2)) * 9;   // uniform -> s_load
      float4 a = make_float4(0.f, 0.f, 0.f, 0.f);
      #pragma unroll
      for (int dy = 0; dy < 3; dy++){
        #pragma unroll
        for (int dx = 0; dx < 3; dx++){
          float4 v = s_in4[w][ly + dy][lx + dx];
          int k = dy * 3 + dx;
          a.x += v.x * wd[k];
          a.y += v.y * wd[9 + k];
          a.z += v.z * wd[18 + k];
          a.w += v.w * wd[27 + k];
        }
      }
      s_dw4[w][lane] = a;
    }
    __syncthreads();

    // pw (8 outputs/wave for this half) + red (half 1 only)
    #pragma unroll
    for (int g = 0; g < 4; g++){
      float4 d = s_dw4[g][lane];
      int cc = c0 + (g << 2);
      #pragma unroll
      for (int j = 0; j < 8; j++){
        const float* wr = wpw + ((half << 5) + (w << 3) + j) * 64 + cc;  // s_load
        pacc[j] += d.x * wr[0] + d.y * wr[1] + d.z * wr[2] + d.w * wr[3];
      }
      if (half){
        float4 cv = s_in4[g][ly + 1][lx + 1];        // raw center for reduce
        #pragma unroll
        for (int j = 0; j < 4; j++){
          const float* wr = wred + ((w << 2) + j) * 64 + cc;
          racc[j] += cv.x * wr[0] + cv.y * wr[1] + cv.z * wr[2] + cv.w * wr[3];
        }
      }
    }
  }

  long sp = ((long)(y0 + ly) << 7) + x0 + lx;
  float* hb = h + ((long)b << 20) + sp;
  int ob = (half << 5) + (w << 3);
  #pragma unroll
  for (int j = 0; j < 8; j++) hb[(long)(ob + j) << 14] = pacc[j];

  if (half){
    float* rb = r + ((long)b << 18) + sp;
    #pragma unroll
    for (int j = 0; j < 4; j++) rb[(long)((w << 2) + j) << 14] = racc[j];

    // BN stats: wave w owns channels 4w..4w+3
    #pragma unroll
    for (int j = 0; j < 4; j++){
      float v = racc[j], s2 = racc[j] * racc[j];
      #pragma unroll
      for (int off = 32; off > 0; off >>= 1){
        v  += __shfl_down(v,  off, 64);
        s2 += __shfl_down(s2, off, 64);
      }
      if (lane == 0){ s_red[w][2 * j] = v; s_red[w][2 * j + 1] = s2; }
    }
    __syncthreads();
    if (t < 32) atomicAdd(&stats[t], s_red[t >> 3][t & 7]);
  }
}

// ---- main involution (unchanged, ~46us): per (b, g, 16x16 tile) ----
// BN finalize folded in; w_span staged in LDS -> ds_read_b128 broadcast
__launch_bounds__(256)
__global__ void k_main(const float* __restrict__ h, const float* __restrict__ r,
                       const float* __restrict__ stats, const float* __restrict__ gamma,
                       const float* __restrict__ beta, const float* __restrict__ wspan,
                       float* __restrict__ out){
  __shared__ float4 s_h4[22][24];                    // [row][col] -> 4 cg contiguous
  __shared__ float4 s_w[196];                        // 49 taps x 4 float4 = 784 w
  int t = threadIdx.x;
  int g = blockIdx.y, b = blockIdx.z;
  int tx0 = (blockIdx.x & 7) << 4, ty0 = (blockIdx.x >> 3) << 4;

  const float4* wsp4 = (const float4*)(wspan + g * 784);
  if (t < 196) s_w[t] = wsp4[t];

  const float* hp = h + (((long)(b * 64 + g * 4)) << 14);
  for (int p = t; p < 484; p += 256){                // 22x22 halo points
    int ry = p / 22, rx = p - ry * 22;
    int yy = ty0 + ry - 3, xx = tx0 + rx - 3;
    float4 v = make_float4(0.f, 0.f, 0.f, 0.f);
    if ((unsigned)yy < 128u && (unsigned)xx < 128u){
      int o = (yy << 7) + xx;
      v.x = hp[o];
      v.y = hp[o + 16384];
      v.z = hp[o + 32768];
      v.w = hp[o + 49152];
    }
    s_h4[ry][rx] = v;
  }

  int ltx = t & 15, lty = t >> 4;
  const float* rp = r + ((long)b << 18) + ((long)(ty0 + lty) << 7) + tx0 + ltx;
  const float inv_n = 1.f / 65536.f;                 // 1/(B*H*W)
  float4 rv4[4];
  #pragma unroll
  for (int c4 = 0; c4 < 4; c4++){
    float tmp[4];
    #pragma unroll
    for (int j = 0; j < 4; j++){
      int c = (c4 << 2) + j;
      float mean = stats[2 * c] * inv_n;             // uniform -> s_load (tiny)
      float var  = stats[2 * c + 1] * inv_n - mean * mean;
      float sc   = gamma[c] * rsqrtf(var + 1e-5f);
      float bi   = beta[c] - mean * sc;
      tmp[j] = fmaxf(rp[(long)c << 14] * sc + bi, 0.f);
    }
    rv4[c4] = make_float4(tmp[0], tmp[1], tmp[2], tmp[3]);
  }
  __syncthreads();

  float acc0 = 0.f, acc1 = 0.f, acc2 = 0.f, acc3 = 0.f;
  #pragma unroll
  for (int kh = 0; kh < 7; kh++){
    #pragma unroll
    for (int kw = 0; kw < 7; kw++){
      int k = kh * 7 + kw;
      float4 w0 = s_w[(k << 2)],     w1 = s_w[(k << 2) + 1];
      float4 w2 = s_w[(k << 2) + 2], w3 = s_w[(k << 2) + 3];
      float kv0 = rv4[0].x * w0.x + rv4[0].y * w0.y + rv4[0].z * w0.z + rv4[0].w * w0.w
                + rv4[1].x * w1.x + rv4[1].y * w1.y + rv4[1].z * w1.z + rv4[1].w * w1.w;
      float kv1 = rv4[2].x * w2.x + rv4[2].y * w2.y + rv4[2].z * w2.z + rv4[2].w * w2.w
                + rv4[3].x * w3.x + rv4[3].y * w3.y + rv4[3].z * w3.z + rv4[3].w * w3.w;
      float kv = kv0 + kv1;
      float4 hv = s_h4[lty + kh][ltx + kw];
      acc0 += kv * hv.x;
      acc1 += kv * hv.y;
      acc2 += kv * hv.z;
      acc3 += kv * hv.w;
    }
  }

  long obase = (((long)(b * 64 + g * 4)) << 14) + ((long)(ty0 + lty) << 7) + tx0 + ltx;
  out[obase]         = acc0;
  out[obase + 16384] = acc1;
  out[obase + 32768] = acc2;
  out[obase + 49152] = acc3;
}

extern "C" void kernel_launch(void* const* d_in, const int* in_sizes, int n_in,
                              void* d_out, int out_size, void* d_ws, size_t ws_size,
                              hipStream_t stream){
  const float* in       = (const float*)d_in[0];
  const float* w_dw     = (const float*)d_in[1];
  const float* w_pw     = (const float*)d_in[2];
  const float* gamma    = (const float*)d_in[3];
  const float* beta     = (const float*)d_in[4];
  const float* w_reduce = (const float*)d_in[5];
  const float* w_span   = (const float*)d_in[6];
  float* out = (float*)d_out;

  float* ws    = (float*)d_ws;
  float* h     = ws;                    // 4194304 floats
  float* r     = ws + 4194304;          // 1048576 floats
  float* stats = ws + 5242880;          // 32 floats

  hipMemsetAsync(stats, 0, 32 * sizeof(float), stream);
  dim3 gf(1024, 2);
  k_front<<<gf, 256, 0, stream>>>(in, w_dw, w_pw, w_reduce, h, r, stats);
  dim3 grid(64, 16, 4);
  k_main <<<grid, 256, 0, stream>>>(h, r, stats, gamma, beta, w_span, out);
}